// Round 3
// baseline (29.572 us; speedup 1.0000x reference)
//
#include <hip/hip_runtime.h>

// Adaptive avg pool 2D: (16, 768, 64, 48) f32 -> (16, 768, 7, 7) f32.
// 2048 blocks x 6 planes/block. Double-buffered HBM->LDS DMA (global_load_lds,
// 16B/lane), ONE raw barrier per plane, stage-2 deferred one plane so ts[] can
// double-buffer. Outputs accumulate in registers, stored once at the end.

#define H_IN 64
#define W_IN 48
#define HO 7
#define WO 7
#define PLANE (H_IN * W_IN)   // 3072 floats = 12 KB
#define PPB 6                 // planes per block (12288 / 2048)
#define TS_N (H_IN * WO)      // 448

typedef __attribute__((address_space(3))) void  lds_void_t;
typedef const __attribute__((address_space(1))) void gbl_void_t;

__global__ __launch_bounds__(256) void
adaptive_pool_kernel(const float* __restrict__ x, float* __restrict__ out) {
    __shared__ float xs[2][PLANE];   // 24 KB double-buffered input plane
    __shared__ float ts[2][TS_N];    // 3.5 KB double-buffered row-pooled [64][7]

    const int tid = threadIdx.x;
    const size_t plane0 = (size_t)blockIdx.x * PPB;
    const float* xp = x + plane0 * PLANE;       // 6 contiguous planes

    // ---- Hoisted per-thread work assignments (identical for every plane) ----
    // Stage 1: item = tid and tid+256 over 448 items.
    const int row0 = tid / WO, ow0 = tid % WO;
    const int ws0  = (ow0 * W_IN) / WO;
    const int we0  = ((ow0 + 1) * W_IN + WO - 1) / WO;
    const float inv0 = 1.0f / (float)(we0 - ws0);
    const int  item1 = tid + 256;
    const bool has1  = item1 < TS_N;            // tid < 192
    const int row1 = item1 / WO, ow1 = item1 % WO;
    const int ws1  = (ow1 * W_IN) / WO;
    const int we1  = ((ow1 + 1) * W_IN + WO - 1) / WO;
    const float inv1 = 1.0f / (float)(we1 - ws1);
    // Stage 2: 49 outputs; H window is always 10 rows for 64->7.
    const bool has2 = tid < HO * WO;
    const int oh = tid / WO, ow2 = tid % WO;
    const int hs = (oh * H_IN) / HO;
    const float invH = 1.0f / 10.0f;

    float oacc[PPB];

    // ---- Prologue: DMA plane 0 -> xs[0] (3 x 16 B per thread) ----
    #pragma unroll
    for (int i = 0; i < 3; ++i) {
        const int f4 = tid + i * 256;
        __builtin_amdgcn_global_load_lds((gbl_void_t*)(xp + f4 * 4),
                                         (lds_void_t*)(&xs[0][f4 * 4]), 16, 0, 0);
    }

    #pragma unroll
    for (int p = 0; p < PPB; ++p) {
        const int b = p & 1;
        // B1: plane p's DMA landed; all prior LDS reads/writes complete.
        asm volatile("s_waitcnt vmcnt(0) lgkmcnt(0)" ::: "memory");
        __builtin_amdgcn_s_barrier();

        // Issue plane p+1 DMA into xs[1-b]; flies under this plane's compute.
        if (p + 1 < PPB) {
            const float* src = xp + (p + 1) * PLANE;
            #pragma unroll
            for (int i = 0; i < 3; ++i) {
                const int f4 = tid + i * 256;
                __builtin_amdgcn_global_load_lds((gbl_void_t*)(src + f4 * 4),
                                                 (lds_void_t*)(&xs[1 - b][f4 * 4]), 16, 0, 0);
            }
        }

        // Stage 2 for plane p-1 (reads ts[1-b], written last iteration).
        if (p > 0 && has2) {
            float s = 0.0f;
            #pragma unroll
            for (int h = 0; h < 10; ++h)
                s += ts[1 - b][(hs + h) * WO + ow2];
            oacc[p - 1] = s * invH;
        }

        // Stage 1 for plane p: xs[b] -> ts[b].
        {
            float s = 0.0f;
            #pragma unroll
            for (int w = 0; w < 8; ++w)
                if (ws0 + w < we0) s += xs[b][row0 * W_IN + ws0 + w];
            ts[b][tid] = s * inv0;
        }
        if (has1) {
            float s = 0.0f;
            #pragma unroll
            for (int w = 0; w < 8; ++w)
                if (ws1 + w < we1) s += xs[b][row1 * W_IN + ws1 + w];
            ts[b][item1] = s * inv1;
        }
    }

    // Epilogue: stage 2 for the last plane (ts[(PPB-1)&1] = ts[1]).
    asm volatile("s_waitcnt lgkmcnt(0)" ::: "memory");
    __builtin_amdgcn_s_barrier();
    if (has2) {
        float s = 0.0f;
        #pragma unroll
        for (int h = 0; h < 10; ++h)
            s += ts[1][(hs + h) * WO + ow2];
        oacc[PPB - 1] = s * invH;
    }

    // Single store pass: 6 x 49 contiguous floats per block.
    if (has2) {
        float* op = out + plane0 * (HO * WO) + tid;
        #pragma unroll
        for (int p = 0; p < PPB; ++p)
            op[p * (HO * WO)] = oacc[p];
    }
}

extern "C" void kernel_launch(void* const* d_in, const int* in_sizes, int n_in,
                              void* d_out, int out_size, void* d_ws, size_t ws_size,
                              hipStream_t stream) {
    const float* x = (const float*)d_in[0];
    float* out = (float*)d_out;
    const int nplanes = in_sizes[0] / PLANE;       // 12288
    const int nblocks = nplanes / PPB;             // 2048
    adaptive_pool_kernel<<<nblocks, 256, 0, stream>>>(x, out);
}

// Round 4
// 28.227 us; speedup vs baseline: 1.0476x; 1.0476x over previous
//
#include <hip/hip_runtime.h>

// Adaptive avg pool 2D: (16, 768, 64, 48) f32 -> (16, 768, 7, 7) f32.
// ONE WAVE PER PLANE, barrier-free. Lane l owns row l (64 rows = 64 lanes):
// 12x global_load_dwordx4 (immediate offsets off one base) pull the whole row
// into registers; 7 W-window sums computed uniformly in registers (no
// divergence); 7 floats -> wave-private LDS strip; wave-local lgkmcnt wait;
// lanes 0..48 do the 10-row H-pool and store 49 contiguous floats.

#define H_IN 64
#define W_IN 48
#define HO 7
#define WO 7
#define PLANE (H_IN * W_IN)   // 3072 floats = 12 KB
#define WPB 4                 // waves (=planes) per block

__global__ __launch_bounds__(256) void
adaptive_pool_kernel(const float* __restrict__ x, float* __restrict__ out) {
    // ts[wave][row][8]: 8-float padded strip, wave-private. 8 KB total.
    __shared__ float ts[WPB][H_IN][8];

    const int tid  = threadIdx.x;
    const int wid  = tid >> 6;
    const int lane = tid & 63;                 // = row index
    const size_t plane = (size_t)blockIdx.x * WPB + wid;

    // ---- Load lane's entire row (48 floats, 192 B, 64B-line aligned) ----
    const float4* rp = reinterpret_cast<const float4*>(x + plane * PLANE + lane * W_IN);
    float4 v[12];
    #pragma unroll
    for (int k = 0; k < 12; ++k) v[k] = rp[k];

    // Unpack to a statically-indexed array (stays in registers).
    float c[W_IN];
    #pragma unroll
    for (int k = 0; k < 12; ++k) {
        c[4*k+0] = v[k].x; c[4*k+1] = v[k].y; c[4*k+2] = v[k].z; c[4*k+3] = v[k].w;
    }

    // ---- W-pool: 7 windows, compile-time bounds, uniform across lanes ----
    // ws = floor(o*48/7), we = ceil((o+1)*48/7): [0,7)[6,14)[13,21)[20,28)[27,35)[34,42)[41,48)
    const int   WS[WO]  = {0, 6, 13, 20, 27, 34, 41};
    const int   WE[WO]  = {7, 14, 21, 28, 35, 42, 48};
    float w[WO];
    #pragma unroll
    for (int o = 0; o < WO; ++o) {
        float s = 0.0f;
        #pragma unroll
        for (int j = WS[o]; j < WE[o]; ++j) s += c[j];
        w[o] = s * (1.0f / (float)(WE[o] - WS[o]));
    }

    // ---- Store strip (contiguous 28 B + 4 B pad garbage-free writes) ----
    *reinterpret_cast<float4*>(&ts[wid][lane][0]) = make_float4(w[0], w[1], w[2], w[3]);
    *reinterpret_cast<float2*>(&ts[wid][lane][4]) = make_float2(w[4], w[5]);
    ts[wid][lane][6] = w[6];

    // Wave-local ordering: all lanes' ds_writes complete before ds_reads.
    asm volatile("s_waitcnt lgkmcnt(0)" ::: "memory");
    __builtin_amdgcn_wave_barrier();

    // ---- H-pool: 49 outputs per wave, window always 10 rows ----
    if (lane < HO * WO) {
        const int oh = lane / WO;
        const int ow = lane % WO;
        const int hs = (oh * H_IN) / HO;       // 0,9,18,27,36,45,54
        float s = 0.0f;
        #pragma unroll
        for (int h = 0; h < 10; ++h) s += ts[wid][hs + h][ow];
        out[plane * (HO * WO) + lane] = s * 0.1f;
    }
}

extern "C" void kernel_launch(void* const* d_in, const int* in_sizes, int n_in,
                              void* d_out, int out_size, void* d_ws, size_t ws_size,
                              hipStream_t stream) {
    const float* x = (const float*)d_in[0];
    float* out = (float*)d_out;
    const int nplanes = in_sizes[0] / PLANE;   // 12288
    const int nblocks = nplanes / WPB;         // 3072
    adaptive_pool_kernel<<<nblocks, 256, 0, stream>>>(x, out);
}